// Round 7
// baseline (442.088 us; speedup 1.0000x reference)
//
#include <hip/hip_runtime.h>
#include <math.h>

#define BB 8
#define NP 2048
#define NAA 512
#define KNN 16
#define KK2 14
#define DE 16
#define NG 64
#define FF 128
#define FF2 128
#define NCAT 39
#define EPSV 1e-6f

// round-to-nearest-even f32 -> bf16 value (kept in f32)
__device__ __forceinline__ float bf16r(float x) {
    unsigned u = __float_as_uint(x);
    u = u + 0x7FFFu + ((u >> 16) & 1u);
    return __uint_as_float(u & 0xFFFF0000u);
}

// ---------------- workspace layout (bytes) ----------------
#define OFF_CENTER   0u
#define OFF_R        262144u
#define OFF_ATTR     1048576u
#define OFF_NBR      2097152u
#define OFF_ATT      3145728u
#define OFF_FEAT     3211264u
#define OFF_POOLED   11599872u
#define OFF_START    13697024u
#define OFF_PARTS    13713536u
#define OFF_PARTQ    13746304u
#define OFF_SS       13779072u

// ================= K1: frames + attr =================
// centers stay RAW f32 (d2 is a reduce -> f32 exact in ref).
// R rows and attr are ONLY consumed as dot operands -> store bf16-rounded.
__global__ __launch_bounds__(256) void k_frames(
    const int* __restrict__ fidx, const int* __restrict__ aidx,
    const float* __restrict__ pc, const float* __restrict__ mframe,
    const float* __restrict__ emb,
    float* __restrict__ center4, float* __restrict__ R12, float* __restrict__ attr16)
{
    int t = blockIdx.x * 256 + threadIdx.x;
    if (t >= BB * NP) return;
    int b = t / NP;
    const float* pcb = pc + (size_t)b * NP * 3;
    int i0 = fidx[t*3+0], i1 = fidx[t*3+1], i2 = fidx[t*3+2];
    float cx = pcb[i0*3+0], cy = pcb[i0*3+1], cz = pcb[i0*3+2];
    float ax = pcb[i1*3+0]-cx, ay = pcb[i1*3+1]-cy, az = pcb[i1*3+2]-cz;
    float bx = pcb[i2*3+0]-cx, by = pcb[i2*3+1]-cy, bz = pcb[i2*3+2]-cz;
    float n1 = sqrtf(ax*ax + ay*ay + az*az) + EPSV;
    float e1x = ax/n1, e1y = ay/n1, e1z = az/n1;
    float nx = ay*bz - az*by;
    float ny = az*bx - ax*bz;
    float nz = ax*by - ay*bx;
    float n3 = sqrtf(nx*nx + ny*ny + nz*nz) + EPSV;
    float e3x = nx/n3, e3y = ny/n3, e3z = nz/n3;
    float e2x = e3y*e1z - e3z*e1y;
    float e2y = e3z*e1x - e3x*e1z;
    float e2z = e3x*e1y - e3y*e1x;

    float4 c4; c4.x = cx; c4.y = cy; c4.z = cz; c4.w = 0.f;
    *(float4*)(center4 + (size_t)t*4) = c4;
    float* Rp = R12 + (size_t)t*12;
    Rp[0]=bf16r(e1x); Rp[1]=bf16r(e1y); Rp[2]=bf16r(e1z);
    Rp[3]=bf16r(e2x); Rp[4]=bf16r(e2y); Rp[5]=bf16r(e2z);
    Rp[6]=bf16r(e3x); Rp[7]=bf16r(e3y); Rp[8]=bf16r(e3z);

    int ai = aidx[t];
    float m = mframe[t];
    const float* er = emb + (size_t)ai * DE;
    float* ap = attr16 + (size_t)t * DE;
    #pragma unroll
    for (int d = 0; d < DE; ++d) ap[d] = bf16r(er[d] * m);
}

// ================= K2: KNN top-16, f32-rn d2 (EXACT R1), lower-index ties ==
__global__ __launch_bounds__(256) void k_knn(
    const float* __restrict__ center4, int* __restrict__ nbr)
{
    __shared__ float sx[NP], sy[NP], sz[NP];
    __shared__ unsigned long long kbuf[32*8*16];
    int b = blockIdx.x >> 6;
    int qchunk = blockIdx.x & 63;
    int t = threadIdx.x;
    const float* cb = center4 + (size_t)b * NP * 4;
    for (int j = t; j < NP; j += 256) {
        float4 c = *(const float4*)(cb + (size_t)j*4);
        sx[j] = c.x; sy[j] = c.y; sz[j] = c.z;
    }
    __syncthreads();
    int qloc = t & 31, split = t >> 5;
    int q = qchunk * 32 + qloc;
    float qx = sx[q], qy = sy[q], qz = sz[q];
    unsigned long long keys[16];
    #pragma unroll
    for (int s = 0; s < 16; ++s) keys[s] = ~0ULL;
    int j0 = split * 256;
    for (int jj = 0; jj < 256; ++jj) {
        int j = j0 + jj;
        float dx = __fsub_rn(qx, sx[j]);
        float dy = __fsub_rn(qy, sy[j]);
        float dz = __fsub_rn(qz, sz[j]);
        float d2 = __fadd_rn(__fadd_rn(__fmul_rn(dx,dx), __fmul_rn(dy,dy)), __fmul_rn(dz,dz));
        unsigned long long key = ((unsigned long long)__float_as_uint(d2) << 32) | (unsigned)j;
        if (key < keys[15]) {
            unsigned long long c = key;
            #pragma unroll
            for (int s = 0; s < 16; ++s) {
                unsigned long long lo = c < keys[s] ? c : keys[s];
                unsigned long long hi = c < keys[s] ? keys[s] : c;
                keys[s] = lo; c = hi;
            }
        }
    }
    unsigned long long* myb = kbuf + ((size_t)qloc*8 + split)*16;
    #pragma unroll
    for (int s = 0; s < 16; ++s) myb[s] = keys[s];
    __syncthreads();
    if (t < 32) {
        unsigned long long arr[16];
        #pragma unroll
        for (int s = 0; s < 16; ++s) arr[s] = ~0ULL;
        for (int sp = 0; sp < 8; ++sp) {
            const unsigned long long* bb = kbuf + ((size_t)t*8 + sp)*16;
            for (int s = 0; s < 16; ++s) {
                unsigned long long key = bb[s];
                if (key >= arr[15]) break;
                unsigned long long c = key;
                #pragma unroll
                for (int u = 0; u < 16; ++u) {
                    unsigned long long lo = c < arr[u] ? c : arr[u];
                    unsigned long long hi = c < arr[u] ? arr[u] : c;
                    arr[u] = lo; c = hi;
                }
            }
        }
        int qg = qchunk * 32 + t;
        int* outp = nbr + ((size_t)b*NP + qg) * KNN;
        #pragma unroll
        for (int s = 0; s < 16; ++s) outp[s] = (int)(arr[s] & 0xFFFFFFFFu);
    }
}

// ================= K3: gauss filter + y + att + feat =================
// All dot operands bf16-rounded (f32 accumulate); elementwise/exp stays f32.
__global__ __launch_bounds__(256) void k_filter(
    const float* __restrict__ center4, const float* __restrict__ R12,
    const float* __restrict__ attr16, const int* __restrict__ nbr,
    const float* __restrict__ mframe,
    const float* __restrict__ mu, const float* __restrict__ sigma,
    const float* __restrict__ Wf, const float* __restrict__ Watt,
    const float* __restrict__ Wfeat,
    float* __restrict__ att, float* __restrict__ feat)
{
    __shared__ float cG[NG*8];
    __shared__ float locS[16*16*4];
    __shared__ float attrnS[16*16*16];
    __shared__ float gaussS[16*16*17];
    __shared__ float ZS[256*16];
    __shared__ float cS[16*4];
    __shared__ float RS[16*12];
    __shared__ int   nbrS[256];
    __shared__ float mfS[16];

    int t = threadIdx.x;
    int blk = blockIdx.x;
    int b = blk / (NP/16);
    int abase = (blk % (NP/16)) * 16;
    size_t gbase = (size_t)b * NP + abase;

    if (t < NG) {
        float s0 = sigma[t*3+0], s1 = sigma[t*3+1], s2 = sigma[t*3+2];
        float i0 = 1.f/(s0*s0 + EPSV), i1 = 1.f/(s1*s1 + EPSV), i2 = 1.f/(s2*s2 + EPSV);
        float m0 = mu[t*3+0], m1 = mu[t*3+1], m2 = mu[t*3+2];
        float* cg = cG + t*8;
        cg[0]=bf16r(i0); cg[1]=bf16r(i1); cg[2]=bf16r(i2);          // dot operand
        cg[3]=bf16r(m0*i0); cg[4]=bf16r(m1*i1); cg[5]=bf16r(m2*i2); // dot operand
        cg[6]=m0*m0*i0 + m1*m1*i1 + m2*m2*i2;                       // reduce: f32
    }
    if (t < 16) {
        float4 c = *(const float4*)(center4 + (gbase + t)*4);
        cS[t*4+0]=c.x; cS[t*4+1]=c.y; cS[t*4+2]=c.z;
        const float* Rp = R12 + (gbase + t)*12;   // already bf16-rounded
        #pragma unroll
        for (int r = 0; r < 9; ++r) RS[t*12+r] = Rp[r];
        mfS[t] = mframe[gbase + t];
    }
    nbrS[t] = nbr[gbase*KNN + t];
    __syncthreads();

    {   // attrn + local = <bf16(delta), bf16(R)>, f32 accum
        int a = t >> 4, k = t & 15;
        int j = nbrS[t];
        size_t gj = (size_t)b*NP + j;
        const float4* ap = (const float4*)(attr16 + gj*DE);  // pre-rounded
        float4 A0 = ap[0], A1 = ap[1], A2 = ap[2], A3 = ap[3];
        float4* dst = (float4*)(attrnS + ((size_t)a*16 + k)*16);
        dst[0]=A0; dst[1]=A1; dst[2]=A2; dst[3]=A3;
        float4 cj = *(const float4*)(center4 + gj*4);
        float dx = bf16r(cj.x - cS[a*4+0]);
        float dy = bf16r(cj.y - cS[a*4+1]);
        float dz = bf16r(cj.z - cS[a*4+2]);
        const float* Rr = RS + a*12;
        float l0 = dx*Rr[0] + dy*Rr[1] + dz*Rr[2];
        float l1 = dx*Rr[3] + dy*Rr[4] + dz*Rr[5];
        float l2 = dx*Rr[6] + dy*Rr[7] + dz*Rr[8];
        float* lp = locS + ((size_t)a*16 + k)*4;
        lp[0]=l0; lp[1]=l1; lp[2]=l2;
    }
    __syncthreads();

    float y8[8];
    #pragma unroll
    for (int s = 0; s < 8; ++s) y8[s] = 0.f;
    int f = t & 127, ah = t >> 7;

    for (int nc = 0; nc < 4; ++nc) {
        {   // gauss: q = <bf16(l^2),bf16(inv_s2)> - 2<bf16(l),bf16(mu*inv_s2)> + c3
            int a = t >> 4, k = t & 15;
            const float* lp = locS + ((size_t)a*16 + k)*4;
            float l0 = lp[0], l1 = lp[1], l2 = lp[2];
            float s0 = bf16r(l0*l0), s1 = bf16r(l1*l1), s2 = bf16r(l2*l2);
            float b0 = bf16r(l0), b1 = bf16r(l1), b2 = bf16r(l2);
            float* gp = gaussS + ((size_t)a*16 + k)*17;
            #pragma unroll
            for (int nl = 0; nl < 16; ++nl) {
                const float* cg = cG + (nc*16 + nl)*8;
                float dotA = s0*cg[0] + s1*cg[1] + s2*cg[2];
                float dotB = b0*cg[3] + b1*cg[4] + b2*cg[5];
                float qv = dotA - 2.f*dotB + cg[6];
                gp[nl] = bf16r(expf(-0.5f*qv));      // dot operand for Z
            }
        }
        __syncthreads();
        {   // Z chunk = <bf16(gauss), bf16(attr)>, f32 accum; store bf16(Z)
            int a = t >> 4, d = t & 15;
            const float* gpA = gaussS + (size_t)a*16*17;
            const float* apA = attrnS + (size_t)a*256 + d;
            #pragma unroll
            for (int nl = 0; nl < 16; ++nl) {
                float acc = 0.f;
                const float* gp = gpA + nl;
                #pragma unroll
                for (int k = 0; k < 16; ++k) acc += gp[k*17] * apA[k*16];
                ZS[(nl*16 + d)*16 + a] = bf16r(acc);  // dot operand for y
            }
        }
        __syncthreads();
        {   // y += <bf16(Z), bf16(Wf)>
            const float* Wp = Wf + (size_t)(nc*256)*FF + f;
            for (int nd = 0; nd < 256; ++nd) {
                float w = bf16r(Wp[(size_t)nd*FF]);
                const float4* zp = (const float4*)(ZS + nd*16 + ah*8);
                float4 z0 = zp[0], z1 = zp[1];
                y8[0] += z0.x*w; y8[1] += z0.y*w; y8[2] += z0.z*w; y8[3] += z0.w*w;
                y8[4] += z1.x*w; y8[5] += z1.y*w; y8[6] += z1.z*w; y8[7] += z1.w*w;
            }
        }
        __syncthreads();
    }

    // y -> relu * mframe -> yS (bf16-rounded: only feeds att/feat dots)
    float* yS = ZS;
    #pragma unroll
    for (int s = 0; s < 8; ++s) {
        int a = ah*8 + s;
        float v = y8[s] > 0.f ? y8[s] : 0.f;
        yS[f*16 + a] = bf16r(v * mfS[a]);
    }
    __syncthreads();

    if (t < 16) {
        float s = 0.f;
        for (int c = 0; c < FF; ++c) s += yS[c*16 + t] * bf16r(Watt[c]);
        att[gbase + t] = s * mfS[t];
    }
    {
        float f8[8];
        #pragma unroll
        for (int s = 0; s < 8; ++s) f8[s] = 0.f;
        for (int c = 0; c < FF; ++c) {
            float w = bf16r(Wfeat[(size_t)c*FF2 + f]);
            const float4* yp = (const float4*)(yS + c*16 + ah*8);
            float4 a0 = yp[0], a1 = yp[1];
            f8[0] += a0.x*w; f8[1] += a0.y*w; f8[2] += a0.z*w; f8[3] += a0.w*w;
            f8[4] += a1.x*w; f8[5] += a1.y*w; f8[6] += a1.z*w; f8[7] += a1.w*w;
        }
        #pragma unroll
        for (int s = 0; s < 8; ++s) {
            int a = ah*8 + s;
            feat[(gbase + a)*FF2 + f] = f8[s] * mfS[a];
        }
    }
}

// ================= K4a =================
__global__ __launch_bounds__(576) void k_start(
    const int* __restrict__ seq_atom, int* __restrict__ start)
{
    int b = blockIdx.x;
    int v = threadIdx.x;
    if (v > NAA) return;
    const int* s = seq_atom + (size_t)b * NP;
    int lo = 0, hi = NP;
    while (lo < hi) {
        int mid = (lo + hi) >> 1;
        if (s[mid] < v) lo = mid + 1; else hi = mid;
    }
    start[b*(NAA+1) + v] = lo;
}

// ================= K4b: pooled = <bf16(w), bf16(feat)> =================
__global__ __launch_bounds__(64) void k_pool(
    const int* __restrict__ seq_aa, const int* __restrict__ start,
    const float* __restrict__ att, const float* __restrict__ feat,
    const float* __restrict__ mseq, float* __restrict__ pooled)
{
    __shared__ int   jS[KK2];
    __shared__ int   dS[KK2];
    __shared__ float avS[KK2];
    __shared__ float wS[KK2];
    int blk = blockIdx.x;
    int b = blk >> 9;
    int a = blk & (NAA - 1);
    int t = threadIdx.x;
    if (t == 0) {
        int v = seq_aa[b*NAA + a];
        const int* st = start + b*(NAA+1);
        int cnt = 0;
        for (int d = 0; cnt < KK2 && d < NAA; ++d) {
            int vlo = v - d;
            if (vlo >= 0) {
                int s0 = st[vlo], s1 = st[vlo+1];
                for (int j = s0; j < s1 && cnt < KK2; ++j) { jS[cnt] = j; dS[cnt] = d; ++cnt; }
            }
            int vhi = v + d;
            if (d > 0 && vhi < NAA) {
                int s0 = st[vhi], s1 = st[vhi+1];
                for (int j = s0; j < s1 && cnt < KK2; ++j) { jS[cnt] = j; dS[cnt] = d; ++cnt; }
            }
        }
        float m = -INFINITY;
        for (int k = 0; k < KK2; ++k) {
            float av = att[(size_t)b*NP + jS[k]];
            avS[k] = av;
            m = fmaxf(m, av);
        }
        float ssum = 0.f;
        for (int k = 0; k < KK2; ++k) {
            float g = (dS[k] == 0) ? 1.f : 0.f;
            float w = g * expf(avS[k] - m);
            wS[k] = w;
            ssum += w;
        }
        float inv = 1.f / (ssum + EPSV);
        for (int k = 0; k < KK2; ++k) wS[k] = bf16r(wS[k] * inv);  // dot operand
    }
    __syncthreads();
    int row = b*NAA + a;
    float m = mseq[row];
    for (int ff = t; ff < FF2; ff += 64) {
        float acc = 0.f;
        #pragma unroll
        for (int k = 0; k < KK2; ++k)
            acc += wS[k] * bf16r(feat[((size_t)b*NP + jS[k])*FF2 + ff]);
        pooled[(size_t)row*FF2 + ff] = acc * m;
    }
}

// ================= K5: batchnorm (f32, deterministic) =================
__global__ __launch_bounds__(128) void k_bnstat1(
    const float* __restrict__ pooled, const float* __restrict__ mseq,
    float* __restrict__ partS, float* __restrict__ partQ)
{
    int g = blockIdx.x, f = threadIdx.x;
    float s = 0.f, q = 0.f;
    for (int r = 0; r < 64; ++r) {
        int row = g*64 + r;
        float m = mseq[row];
        float x = pooled[(size_t)row*FF2 + f];
        s += x*m; q += x*x*m;
    }
    partS[g*FF2 + f] = s;
    partQ[g*FF2 + f] = q;
}

__global__ __launch_bounds__(128) void k_bnstat2(
    const float* __restrict__ partS, const float* __restrict__ partQ,
    const float* __restrict__ mseq,
    const float* __restrict__ gamma, const float* __restrict__ beta,
    float* __restrict__ scaleshift)
{
    __shared__ float msums[128];
    int f = threadIdx.x;
    float mm = 0.f;
    for (int r = f; r < BB*NAA; r += 128) mm += mseq[r];
    msums[f] = mm;
    __syncthreads();
    for (int s = 64; s > 0; s >>= 1) {
        if (f < s) msums[f] += msums[f + s];
        __syncthreads();
    }
    float Sm = msums[0];
    float msum = Sm + EPSV;
    float s = 0.f, q = 0.f;
    for (int g = 0; g < 64; ++g) { s += partS[g*FF2 + f]; q += partQ[g*FF2 + f]; }
    float mean = s / msum;
    float var = (q - 2.f*mean*s + mean*mean*Sm) / msum;
    float rstd = 1.f / sqrtf(var + 1e-5f);
    float sc = rstd * gamma[f];
    scaleshift[f] = sc;
    scaleshift[FF2 + f] = beta[f] - mean*sc;
}

__global__ __launch_bounds__(256) void k_bnapply(
    const float* __restrict__ pooled, const float* __restrict__ scaleshift,
    const float* __restrict__ mseq, float* __restrict__ out)
{
    int idx = blockIdx.x*256 + threadIdx.x;
    if (idx < BB*NAA*FF2) {
        int f = idx & (FF2 - 1);
        int row = idx >> 7;
        float v = pooled[idx]*scaleshift[f] + scaleshift[FF2 + f];
        v = v > 0.f ? v : 0.f;
        out[idx] = v * mseq[row];
    }
    if (idx < BB*NAA) out[BB*NAA*FF2 + idx] = mseq[idx];
}

// ================= launch =================
extern "C" void kernel_launch(void* const* d_in, const int* in_sizes, int n_in,
                              void* d_out, int out_size, void* d_ws, size_t ws_size,
                              hipStream_t stream)
{
    const int*   fidx   = (const int*)  d_in[0];
    const int*   aidx   = (const int*)  d_in[1];
    const int*   seqat  = (const int*)  d_in[2];
    const int*   seqaa  = (const int*)  d_in[3];
    const float* pc     = (const float*)d_in[4];
    const float* mframe = (const float*)d_in[5];
    const float* mseq   = (const float*)d_in[6];
    const float* emb    = (const float*)d_in[7];
    const float* gmu    = (const float*)d_in[8];
    const float* gsig   = (const float*)d_in[9];
    const float* Wf     = (const float*)d_in[10];
    const float* Watt   = (const float*)d_in[11];
    const float* Wfeat  = (const float*)d_in[12];
    const float* gamma  = (const float*)d_in[13];
    const float* beta   = (const float*)d_in[14];

    char* ws = (char*)d_ws;
    float* center4 = (float*)(ws + OFF_CENTER);
    float* R12     = (float*)(ws + OFF_R);
    float* attr16  = (float*)(ws + OFF_ATTR);
    int*   nbr     = (int*)  (ws + OFF_NBR);
    float* att     = (float*)(ws + OFF_ATT);
    float* feat    = (float*)(ws + OFF_FEAT);
    float* pooled  = (float*)(ws + OFF_POOLED);
    int*   start   = (int*)  (ws + OFF_START);
    float* partS   = (float*)(ws + OFF_PARTS);
    float* partQ   = (float*)(ws + OFF_PARTQ);
    float* ss      = (float*)(ws + OFF_SS);
    float* outp    = (float*)d_out;

    hipLaunchKernelGGL(k_frames, dim3(64), dim3(256), 0, stream,
                       fidx, aidx, pc, mframe, emb, center4, R12, attr16);
    hipLaunchKernelGGL(k_knn, dim3(512), dim3(256), 0, stream, center4, nbr);
    hipLaunchKernelGGL(k_filter, dim3(1024), dim3(256), 0, stream,
                       center4, R12, attr16, nbr, mframe, gmu, gsig,
                       Wf, Watt, Wfeat, att, feat);
    hipLaunchKernelGGL(k_start, dim3(BB), dim3(576), 0, stream, seqat, start);
    hipLaunchKernelGGL(k_pool, dim3(BB*NAA), dim3(64), 0, stream,
                       seqaa, start, att, feat, mseq, pooled);
    hipLaunchKernelGGL(k_bnstat1, dim3(64), dim3(128), 0, stream,
                       pooled, mseq, partS, partQ);
    hipLaunchKernelGGL(k_bnstat2, dim3(1), dim3(128), 0, stream,
                       partS, partQ, mseq, gamma, beta, ss);
    hipLaunchKernelGGL(k_bnapply, dim3((BB*NAA*FF2 + 255)/256), dim3(256), 0, stream,
                       pooled, ss, mseq, outp);
}